// Round 8
// baseline (265.294 us; speedup 1.0000x reference)
//
#include <hip/hip_runtime.h>
#include <hip/hip_bf16.h>

// SMPL collapsed-form. R8: R6's exact math, fused into k0 + one persistent
// mega-kernel (k1 + reduce/prep + k3 + k4) with software grid barriers.
// B=1024, V=6890, NB=10, NJ=24, NP=207, NK=19.
constexpr int Vn   = 6890;
constexpr int VC3  = 20670;   // V*3
constexpr int NKB  = 216;     // K blocks of 32 (K padded to 6912)
constexpr int QT   = 224;     // q rows: [ones, v_template, 10 shapedirs, 207 posedirs]
constexpr int NMG  = 14;      // QT/16 m-frag groups per c-plane
constexpr int NCOL = 480;     // 456 (k,j) cols + 24 Jreg cols
constexpr int WR   = 1440;    // W rows transposed = 480*3
constexpr int MC   = 1368;    // 456*3
constexpr int KSEG = 8;       // K split for k1 (216/8 = 27 kb per wave)
constexpr int NBLK = 336;     // mega grid: 336 blocks x 256 thr = 1344 waves

using bf16x8  = __attribute__((ext_vector_type(8))) short;
using floatx4 = __attribute__((ext_vector_type(4))) float;

__device__ __forceinline__ unsigned short f2bf(float f) {
    unsigned int u = __float_as_uint(f);
    unsigned int r = (u + 0x7FFFu + ((u >> 16) & 1u)) >> 16;
    return (unsigned short)r;
}

// ---------- K0: build Af [42][216] frags, Bf [32][216] frags, zero Jacc+bar ----------
__global__ __launch_bounds__(256) void k0_build(
    const float* __restrict__ vt, const float* __restrict__ sdirs,
    const float* __restrict__ pdirs, const float* __restrict__ Jreg,
    const float* __restrict__ jreg, const float* __restrict__ wts,
    unsigned short* __restrict__ Af, unsigned short* __restrict__ Bf,
    float* __restrict__ Jacc, unsigned* __restrict__ bar)
{
    int bx = blockIdx.x, t = threadIdx.x;
    if (bx < 756) {                           // ---- part A: 224 q x 864 chunks of 8 v
        int g = bx * 256 + t;                 // < 193536 = 224*864
        int q = g / 864, u = g % 864;
        int v0 = u * 8, base = 3 * v0;
        float buf[24];
        if (q == 0) {
            #pragma unroll
            for (int i = 0; i < 24; ++i) buf[i] = (v0 + i / 3 < Vn) ? 1.f : 0.f;
        } else {
            const float* src = nullptr;
            if (q == 1) src = vt;
            else if (q >= 2 && q < 12)   src = sdirs + (size_t)(q - 2) * VC3;
            else if (q >= 12 && q < 219) src = pdirs + (size_t)(q - 12) * VC3;
            if (src && base + 23 < VC3) {
                #pragma unroll
                for (int i = 0; i < 12; ++i) {     // rows only 8B-aligned -> float2
                    float2 f = *(const float2*)(src + base + 2 * i);
                    buf[2 * i] = f.x; buf[2 * i + 1] = f.y;
                }
            } else {
                #pragma unroll
                for (int i = 0; i < 24; ++i)
                    buf[i] = (src && base + i < VC3) ? src[base + i] : 0.f;
            }
        }
        int kb = u >> 2, quad = u & 3, mg = q >> 4;
        size_t foff = (size_t)((q & 15) + quad * 16) * 8;
        #pragma unroll
        for (int c = 0; c < 3; ++c) {
            bf16x8 o;
            #pragma unroll
            for (int j = 0; j < 8; ++j) o[j] = (short)f2bf(buf[3 * j + c]);
            *(bf16x8*)(Af + ((size_t)(c * NMG + mg) * NKB + kb) * 512 + foff) = o;
        }
        return;
    }
    bx -= 756;
    if (bx < 108) {                           // ---- part B (108 blocks, 64 v each)
        int v0 = bx * 64;
        __shared__ float js[64 * 19], wsh[64 * 24], Jsh[64 * 24];
        for (int i = t; i < 64 * 19; i += 256)
            js[i] = (v0 * 19 + i < Vn * 19) ? jreg[v0 * 19 + i] : 0.f;
        for (int i = t; i < 64 * 24; i += 256) {
            wsh[i] = (v0 * 24 + i < Vn * 24) ? wts[v0 * 24 + i] : 0.f;
            Jsh[i] = (v0 * 24 + i < Vn * 24) ? Jreg[v0 * 24 + i] : 0.f;
        }
        __syncthreads();
        for (int s = t; s < 4096; s += 256) { // 512 cols x 8 v-groups
            int col = s >> 3, vg = s & 7;
            int kb = (v0 >> 5) + (vg >> 2);
            bf16x8 o;
            #pragma unroll
            for (int j = 0; j < 8; ++j) {
                int vl = vg * 8 + j;
                float val = 0.f;
                if (col < 456)      val = js[vl * 19 + col / 24] * wsh[vl * 24 + col % 24];
                else if (col < 480) val = Jsh[vl * 24 + (col - 456)];
                o[j] = (short)f2bf(val);
            }
            *(bf16x8*)(Bf + ((size_t)(col >> 4) * NKB + kb) * 512
                          + (size_t)((col & 15) + (vg & 3) * 16) * 8) = o;
        }
        return;
    }
    // ---- part C: zero Jacc (792 floats) + barrier state
    for (int i = t; i < 792; i += 256) Jacc[i] = 0.f;
    if (t == 0) bar[0] = 0u;
}

// ---------- grid barrier: monotonic counter, agent scope ----------
__device__ __forceinline__ void gbar(unsigned* bar, unsigned target) {
    __syncthreads();
    if (threadIdx.x == 0) {
        __hip_atomic_fetch_add(&bar[0], 1u, __ATOMIC_ACQ_REL, __HIP_MEMORY_SCOPE_AGENT);
        while (__hip_atomic_load(&bar[0], __ATOMIC_ACQUIRE, __HIP_MEMORY_SCOPE_AGENT) < target)
            __builtin_amdgcn_s_sleep(2);
    }
    __syncthreads();
}

// ---------- k1 wave body (identical math to R6 k1_mfma) ----------
__device__ __forceinline__ void k1_load(bf16x8 (&a)[2], bf16x8 (&b)[4],
    const unsigned short* __restrict__ ap, const unsigned short* __restrict__ bp, int i)
{
    a[0] = *(const bf16x8*)(ap + (size_t)(0 * NKB + i) * 512);
    a[1] = *(const bf16x8*)(ap + (size_t)(1 * NKB + i) * 512);
    b[0] = *(const bf16x8*)(bp + (size_t)(0 * NKB + i) * 512);
    b[1] = *(const bf16x8*)(bp + (size_t)(1 * NKB + i) * 512);
    b[2] = *(const bf16x8*)(bp + (size_t)(2 * NKB + i) * 512);
    b[3] = *(const bf16x8*)(bp + (size_t)(3 * NKB + i) * 512);
}

__device__ void k1_wave(int wid, int l,
    const unsigned short* __restrict__ Af, const unsigned short* __restrict__ Bf,
    float* __restrict__ P, float* __restrict__ Jacc)
{
    int kseg = wid / 168; int r = wid % 168;
    int c = r / 56; r %= 56;
    int mt = r >> 3, nt = r & 7;
    int kb0 = kseg * 27;

    const unsigned short* ap = Af + ((size_t)(c * NMG + mt * 2) * NKB + kb0) * 512 + l * 8;
    const unsigned short* bp = Bf + ((size_t)(nt * 4) * NKB + kb0) * 512 + l * 8;

    floatx4 acc[2][4];
    #pragma unroll
    for (int mi = 0; mi < 2; ++mi)
        #pragma unroll
        for (int ni = 0; ni < 4; ++ni) acc[mi][ni] = floatx4{0.f, 0.f, 0.f, 0.f};

    bf16x8 a[4][2], b[4][4];
    k1_load(a[0], b[0], ap, bp, 0);
    k1_load(a[1], b[1], ap, bp, 1);
    k1_load(a[2], b[2], ap, bp, 2);
    #pragma unroll
    for (int i = 0; i < 27; ++i) {
        int pf = (i + 3 < 27) ? i + 3 : 26;
        k1_load(a[(i + 3) & 3], b[(i + 3) & 3], ap, bp, pf);
        bf16x8 (&ac)[2] = a[i & 3];
        bf16x8 (&bc)[4] = b[i & 3];
        #pragma unroll
        for (int mi = 0; mi < 2; ++mi)
            #pragma unroll
            for (int ni = 0; ni < 4; ++ni)
                acc[mi][ni] = __builtin_amdgcn_mfma_f32_16x16x32_bf16(ac[mi], bc[ni], acc[mi][ni], 0, 0, 0);
    }
    float* Ps = P + (size_t)kseg * WR * QT;
    int lr = l & 15, rq = (l >> 4) * 4;
    #pragma unroll
    for (int mi = 0; mi < 2; ++mi)
        #pragma unroll
        for (int ni = 0; ni < 4; ++ni) {
            int col = nt * 64 + ni * 16 + lr;
            if (col < NCOL) {
                int q0 = mt * 32 + mi * 16 + rq;
                *(floatx4*)(Ps + (size_t)(col * 3 + c) * QT + q0) = acc[mi][ni];
            }
        }
    if (mt == 0 && nt == 7 && rq < 12) {
        #pragma unroll
        for (int ni = 0; ni < 2; ++ni) {
            int col = 448 + ni * 16 + lr;
            if (col >= 456 && col < 480) {
                #pragma unroll
                for (int rr = 0; rr < 4; ++rr) {
                    int q = rq + rr;
                    if (q >= 1 && q < 12)
                        atomicAdd(&Jacc[(size_t)((col - 456) * 3 + c) * 11 + (q - 1)],
                                  acc[0][ni][rr]);
                }
            }
        }
    }
}

// ---------- MEGA: phase B (k1) -> C (reduce+prep) -> D (k3) -> E (k4) ----------
__global__ __launch_bounds__(256, 2) void mega(
    const unsigned short* __restrict__ Af, const unsigned short* __restrict__ Bf,
    float* __restrict__ P, float* __restrict__ Jacc,
    const float* __restrict__ beta, const float* __restrict__ theta,
    unsigned short* __restrict__ Wb3, float* __restrict__ w1g,
    unsigned short* __restrict__ xbf, float* __restrict__ RAg, float* __restrict__ tAg,
    float* __restrict__ Mg, const float* __restrict__ trans, float* __restrict__ out,
    unsigned* __restrict__ bar)
{
    __shared__ __align__(16) float smem[7080];   // 28.3 KB, reused per phase
    int t = threadIdx.x;

    // ---------------- phase B: k1 (4 independent waves per block) ----------------
    {
        int wid = blockIdx.x * 4 + (t >> 6);     // 0..1343
        k1_wave(wid, t & 63, Af, Bf, P, Jacc);
    }
    gbar(bar, NBLK);

    // ---------------- phase C1: reduce P -> Wb3 + w1g (flat threads) ----------------
    {
        int g = blockIdx.x * 256 + t;
        if (g < WR * 28) {
            int colc = g / 28, q0 = (g % 28) * 8;
            float v[8] = {0, 0, 0, 0, 0, 0, 0, 0};
            #pragma unroll
            for (int s = 0; s < KSEG; ++s) {
                const float4* p = (const float4*)(P + ((size_t)s * WR + colc) * QT + q0);
                float4 x0 = p[0], x1 = p[1];
                v[0] += x0.x; v[1] += x0.y; v[2] += x0.z; v[3] += x0.w;
                v[4] += x1.x; v[5] += x1.y; v[6] += x1.z; v[7] += x1.w;
            }
            if (colc < 1408) {
                bf16x8 o;
                #pragma unroll
                for (int j = 0; j < 8; ++j)
                    o[j] = (short)((colc < MC) ? f2bf(v[j]) : 0);
                *(bf16x8*)(Wb3 + ((size_t)(colc >> 4) * 7 + (q0 >> 5)) * 512
                               + (size_t)((colc & 15) + ((q0 >> 3) & 3) * 16) * 8) = o;
            }
            if (q0 == 0 && colc % 3 == 0 && colc < MC) w1g[colc / 3] = v[0];
        }
    }
    // ---------------- phase C2: per-batch prep, one wave per b ----------------
    if (blockIdx.x < 256) {
        int widx = t >> 6, l = t & 63;
        int b = blockIdx.x * 4 + widx;           // 0..1023
        float* Rs   = smem + widx * 640;         // 216
        float* Jl   = Rs + 216;                  // 72
        float* resR = Jl + 72;                   // 216
        float* rest = resR + 216;                // 72
        float* bet  = rest + 72;                 // 10

        if (l < 10) bet[l] = beta[b * 10 + l];
        if (l < 24) {
            float t0 = theta[b * 72 + l * 3 + 0];
            float t1 = theta[b * 72 + l * 3 + 1];
            float t2 = theta[b * 72 + l * 3 + 2];
            float e0 = t0 + 1e-8f, e1 = t1 + 1e-8f, e2 = t2 + 1e-8f;
            float angle = sqrtf(e0 * e0 + e1 * e1 + e2 * e2);
            float half = 0.5f * angle;
            float sh = sinf(half), ch = cosf(half);
            float s = sh / angle;
            float qx = t0 * s, qy = t1 * s, qz = t2 * s;
            float qn = sqrtf(ch * ch + qx * qx + qy * qy + qz * qz);
            float w = ch / qn, x = qx / qn, y = qy / qn, z = qz / qn;
            Rs[l * 9 + 0] = 1.f - 2.f * (y * y + z * z);
            Rs[l * 9 + 1] = 2.f * (x * y - w * z);
            Rs[l * 9 + 2] = 2.f * (x * z + w * y);
            Rs[l * 9 + 3] = 2.f * (x * y + w * z);
            Rs[l * 9 + 4] = 1.f - 2.f * (x * x + z * z);
            Rs[l * 9 + 5] = 2.f * (y * z - w * x);
            Rs[l * 9 + 6] = 2.f * (x * z - w * y);
            Rs[l * 9 + 7] = 2.f * (y * z + w * x);
            Rs[l * 9 + 8] = 1.f - 2.f * (x * x + y * y);
        }
        __syncthreads();
        if (l < 64) {
            for (int idx = l; idx < 72; idx += 64) {
                const float* basep = Jacc + (size_t)idx * 11;
                float acc = basep[0];
                #pragma unroll
                for (int n = 0; n < 10; ++n) acc += bet[n] * basep[1 + n];
                Jl[idx] = acc;
            }
        }
        for (int q = l; q < QT; q += 64) {
            float xv = 0.f;
            if (q == 1) xv = 1.f;
            else if (q >= 2 && q < 12) xv = bet[q - 2];
            else if (q >= 12 && q < 219) {
                int p = q - 12;
                int jj = 1 + p / 9, e = p % 9;
                float rr = Rs[jj * 9 + e];
                if (e == 0 || e == 4 || e == 8) rr -= 1.f;
                xv = rr;
            }
            xbf[((size_t)(b >> 4) * 7 + (q >> 5)) * 512
                + (size_t)((b & 15) + ((q >> 3) & 3) * 16) * 8 + (q & 7)] = f2bf(xv);
        }
        __syncthreads();
        if (l == 0) {
            const int par[24] = {-1,0,0,0,1,2,3,4,5,6,7,8,9,9,9,12,13,14,16,17,18,19,20,21};
            #pragma unroll
            for (int rr = 0; rr < 3; ++rr) {
                resR[0 * 9 + rr * 3 + 0] =  Rs[rr * 3 + 0];
                resR[0 * 9 + rr * 3 + 1] = -Rs[rr * 3 + 1];
                resR[0 * 9 + rr * 3 + 2] = -Rs[rr * 3 + 2];
                rest[rr] = Jl[rr];
            }
            for (int i = 1; i < 24; ++i) {
                int p = par[i];
                float t0 = Jl[i * 3 + 0] - Jl[p * 3 + 0];
                float t1 = Jl[i * 3 + 1] - Jl[p * 3 + 1];
                float t2 = Jl[i * 3 + 2] - Jl[p * 3 + 2];
                #pragma unroll
                for (int rr = 0; rr < 3; ++rr) {
                    float a0 = resR[p * 9 + rr * 3 + 0], a1 = resR[p * 9 + rr * 3 + 1], a2 = resR[p * 9 + rr * 3 + 2];
                    resR[i * 9 + rr * 3 + 0] = a0 * Rs[i * 9 + 0] + a1 * Rs[i * 9 + 3] + a2 * Rs[i * 9 + 6];
                    resR[i * 9 + rr * 3 + 1] = a0 * Rs[i * 9 + 1] + a1 * Rs[i * 9 + 4] + a2 * Rs[i * 9 + 7];
                    resR[i * 9 + rr * 3 + 2] = a0 * Rs[i * 9 + 2] + a1 * Rs[i * 9 + 5] + a2 * Rs[i * 9 + 8];
                    rest[i * 3 + rr] = a0 * t0 + a1 * t1 + a2 * t2 + rest[p * 3 + rr];
                }
            }
        }
        __syncthreads();
        for (int idx = l; idx < 216; idx += 64)
            RAg[(size_t)b * 216 + idx] = resR[idx];
        if (l < 72) {
            int j = l / 3, c = l % 3;
            tAg[(size_t)b * 72 + l] = rest[j * 3 + c]
                - (resR[j * 9 + c * 3 + 0] * Jl[j * 3 + 0] + resR[j * 9 + c * 3 + 1] * Jl[j * 3 + 1]
                 + resR[j * 9 + c * 3 + 2] * Jl[j * 3 + 2]);
        }
    }
    gbar(bar, 2 * NBLK);

    // ---------------- phase D: k3 (704 independent waves) ----------------
    {
        int wt = blockIdx.x * 4 + (t >> 6);
        if (wt < 704) {
            int blk = wt >> 2, w = wt & 3, l = t & 63;
            int wm = w & 1, wn = w >> 1;
            int ct = blk % 22, bt = blk / 22;
            int mg0 = ct * 4 + wm * 2;
            int bg0 = bt * 8 + wn * 4;
            const unsigned short* ap = Wb3 + (size_t)mg0 * 7 * 512 + l * 8;
            const unsigned short* bp = xbf + (size_t)bg0 * 7 * 512 + l * 8;

            floatx4 acc[2][4];
            #pragma unroll
            for (int mi = 0; mi < 2; ++mi)
                #pragma unroll
                for (int ni = 0; ni < 4; ++ni) acc[mi][ni] = floatx4{0.f, 0.f, 0.f, 0.f};

            #pragma unroll
            for (int kk = 0; kk < 7; ++kk) {
                bf16x8 a0 = *(const bf16x8*)(ap + (size_t)(0 * 7 + kk) * 512);
                bf16x8 a1 = *(const bf16x8*)(ap + (size_t)(1 * 7 + kk) * 512);
                bf16x8 b0 = *(const bf16x8*)(bp + (size_t)(0 * 7 + kk) * 512);
                bf16x8 b1 = *(const bf16x8*)(bp + (size_t)(1 * 7 + kk) * 512);
                bf16x8 b2 = *(const bf16x8*)(bp + (size_t)(2 * 7 + kk) * 512);
                bf16x8 b3 = *(const bf16x8*)(bp + (size_t)(3 * 7 + kk) * 512);
                acc[0][0] = __builtin_amdgcn_mfma_f32_16x16x32_bf16(a0, b0, acc[0][0], 0, 0, 0);
                acc[0][1] = __builtin_amdgcn_mfma_f32_16x16x32_bf16(a0, b1, acc[0][1], 0, 0, 0);
                acc[0][2] = __builtin_amdgcn_mfma_f32_16x16x32_bf16(a0, b2, acc[0][2], 0, 0, 0);
                acc[0][3] = __builtin_amdgcn_mfma_f32_16x16x32_bf16(a0, b3, acc[0][3], 0, 0, 0);
                acc[1][0] = __builtin_amdgcn_mfma_f32_16x16x32_bf16(a1, b0, acc[1][0], 0, 0, 0);
                acc[1][1] = __builtin_amdgcn_mfma_f32_16x16x32_bf16(a1, b1, acc[1][1], 0, 0, 0);
                acc[1][2] = __builtin_amdgcn_mfma_f32_16x16x32_bf16(a1, b2, acc[1][2], 0, 0, 0);
                acc[1][3] = __builtin_amdgcn_mfma_f32_16x16x32_bf16(a1, b3, acc[1][3], 0, 0, 0);
            }
            int lr = l & 15, rq = (l >> 4) * 4;
            #pragma unroll
            for (int mi = 0; mi < 2; ++mi)
                #pragma unroll
                for (int ni = 0; ni < 4; ++ni) {
                    int b  = bt * 128 + wn * 64 + ni * 16 + lr;
                    int cc = (mg0 + mi) * 16 + rq;
                    if (cc < MC)
                        *(floatx4*)(Mg + (size_t)b * MC + cc) = acc[mi][ni];
                }
        }
    }
    gbar(bar, 3 * NBLK);

    // ---------------- phase E: k4 combine (blocks 0..255) ----------------
    if (blockIdx.x < 256) {
        float* w1s = smem;            // 456
        float* Ms  = smem + 456;      // 4*MC = 5472
        float* RAs = smem + 5928;     // 864
        float* tAs = smem + 6792;     // 288
        int b0 = blockIdx.x * 4;
        for (int i = t; i < 456; i += 256) w1s[i] = w1g[i];
        for (int i = t; i < 4 * MC; i += 256) Ms[i] = Mg[(size_t)b0 * MC + i];
        for (int i = t; i < 4 * 216; i += 256) RAs[i] = RAg[(size_t)b0 * 216 + i];
        for (int i = t; i < 4 * 72; i += 256) tAs[i] = tAg[(size_t)b0 * 72 + i];
        __syncthreads();
        if (t < 228) {
            int lb = t / 57, kc = t % 57;
            int k = kc / 3, c = kc % 3;
            int b = b0 + lb;
            float acc = trans[b * 3 + c];
            const float* Mrow = Ms + lb * MC;
            const float* RAr  = RAs + lb * 216;
            const float* tAr  = tAs + lb * 72;
            #pragma unroll
            for (int j = 0; j < 24; ++j) {
                int kj = k * 24 + j;
                float m0 = Mrow[kj * 3 + 0], m1 = Mrow[kj * 3 + 1], m2 = Mrow[kj * 3 + 2];
                acc += RAr[j * 9 + c * 3 + 0] * m0
                     + RAr[j * 9 + c * 3 + 1] * m1
                     + RAr[j * 9 + c * 3 + 2] * m2
                     + tAr[j * 3 + c] * w1s[kj];
            }
            out[b * 57 + kc] = acc;
        }
    }
}

extern "C" void kernel_launch(void* const* d_in, const int* in_sizes, int n_in,
                              void* d_out, int out_size, void* d_ws, size_t ws_size,
                              hipStream_t stream)
{
    const float* beta  = (const float*)d_in[0];
    const float* theta = (const float*)d_in[1];
    const float* trans = (const float*)d_in[2];
    const float* vt    = (const float*)d_in[3];
    const float* sdirs = (const float*)d_in[4];
    const float* Jreg  = (const float*)d_in[5];
    const float* pdirs = (const float*)d_in[6];
    const float* jreg  = (const float*)d_in[7];
    const float* wts   = (const float*)d_in[8];
    float* out = (float*)d_out;
    int B = in_sizes[0] / 10;   // 1024

    // workspace layout (~35 MB), all 16B-aligned
    unsigned short* Af  = (unsigned short*)d_ws;                 // 42*216*512
    unsigned short* Bf  = Af + (size_t)42 * NKB * 512;           // 32*216*512
    unsigned short* Wb3 = Bf + (size_t)32 * NKB * 512;           // 88*7*512
    unsigned short* xbf = Wb3 + (size_t)88 * 7 * 512;            // 64*7*512
    float* P    = (float*)(xbf + (size_t)64 * 7 * 512);          // KSEG*WR*QT
    float* Jacc = P + (size_t)KSEG * WR * QT;                    // 792
    float* w1g  = Jacc + 792;                                    // 456
    float* RAg  = w1g + 456;                                     // B*216
    float* tAg  = RAg + (size_t)B * 216;                         // B*72
    float* Mg   = tAg + (size_t)B * 72;                          // B*MC
    unsigned* bar = (unsigned*)(Mg + (size_t)B * MC);            // 1

    k0_build<<<dim3(756 + 108 + 1), 256, 0, stream>>>(
        vt, sdirs, pdirs, Jreg, jreg, wts, Af, Bf, Jacc, bar);
    mega<<<dim3(NBLK), 256, 0, stream>>>(
        Af, Bf, P, Jacc, beta, theta, Wb3, w1g, xbf, RAg, tAg, Mg, trans, out, bar);
}

// Round 9
// 194.000 us; speedup vs baseline: 1.3675x; 1.3675x over previous
//
#include <hip/hip_runtime.h>
#include <hip/hip_bf16.h>

// SMPL collapsed-form. R9: R6 structure; k1 with KSEG=12 + depth-3 prefetch
// (low register pressure, 2016 waves); tail (reduce/prep + k3 + k4) fused into
// one 256-block kernel with grid barriers. k0 and all math identical to R6.
// B=1024, V=6890, NB=10, NJ=24, NP=207, NK=19.
constexpr int Vn   = 6890;
constexpr int VC3  = 20670;   // V*3
constexpr int NKB  = 216;     // K blocks of 32 (K padded to 6912)
constexpr int QT   = 224;     // q rows: [ones, v_template, 10 shapedirs, 207 posedirs]
constexpr int NMG  = 14;      // QT/16 m-frag groups per c-plane
constexpr int NCOL = 480;     // 456 (k,j) cols + 24 Jreg cols
constexpr int WR   = 1440;    // W rows transposed = 480*3
constexpr int MC   = 1368;    // 456*3
constexpr int KSEG = 12;      // K split for k1 (216/12 = 18 kb per wave)
constexpr int KCH  = 18;      // k-blocks per wave

using bf16x8  = __attribute__((ext_vector_type(8))) short;
using floatx4 = __attribute__((ext_vector_type(4))) float;

__device__ __forceinline__ unsigned short f2bf(float f) {
    unsigned int u = __float_as_uint(f);
    unsigned int r = (u + 0x7FFFu + ((u >> 16) & 1u)) >> 16;
    return (unsigned short)r;
}

// ---------- K0: build Af [42][216] frags, Bf [32][216] frags, zero Jacc+bar ----------
__global__ __launch_bounds__(256) void k0_build(
    const float* __restrict__ vt, const float* __restrict__ sdirs,
    const float* __restrict__ pdirs, const float* __restrict__ Jreg,
    const float* __restrict__ jreg, const float* __restrict__ wts,
    unsigned short* __restrict__ Af, unsigned short* __restrict__ Bf,
    float* __restrict__ Jacc, unsigned* __restrict__ bar)
{
    int bx = blockIdx.x, t = threadIdx.x;
    if (bx < 756) {                           // ---- part A: 224 q x 864 chunks of 8 v
        int g = bx * 256 + t;                 // < 193536 = 224*864
        int q = g / 864, u = g % 864;
        int v0 = u * 8, base = 3 * v0;
        float buf[24];
        if (q == 0) {
            #pragma unroll
            for (int i = 0; i < 24; ++i) buf[i] = (v0 + i / 3 < Vn) ? 1.f : 0.f;
        } else {
            const float* src = nullptr;
            if (q == 1) src = vt;
            else if (q >= 2 && q < 12)   src = sdirs + (size_t)(q - 2) * VC3;
            else if (q >= 12 && q < 219) src = pdirs + (size_t)(q - 12) * VC3;
            if (src && base + 23 < VC3) {
                #pragma unroll
                for (int i = 0; i < 12; ++i) {     // rows only 8B-aligned -> float2
                    float2 f = *(const float2*)(src + base + 2 * i);
                    buf[2 * i] = f.x; buf[2 * i + 1] = f.y;
                }
            } else {
                #pragma unroll
                for (int i = 0; i < 24; ++i)
                    buf[i] = (src && base + i < VC3) ? src[base + i] : 0.f;
            }
        }
        int kb = u >> 2, quad = u & 3, mg = q >> 4;
        size_t foff = (size_t)((q & 15) + quad * 16) * 8;
        #pragma unroll
        for (int c = 0; c < 3; ++c) {
            bf16x8 o;
            #pragma unroll
            for (int j = 0; j < 8; ++j) o[j] = (short)f2bf(buf[3 * j + c]);
            *(bf16x8*)(Af + ((size_t)(c * NMG + mg) * NKB + kb) * 512 + foff) = o;
        }
        return;
    }
    bx -= 756;
    if (bx < 108) {                           // ---- part B (108 blocks, 64 v each)
        int v0 = bx * 64;
        __shared__ float js[64 * 19], wsh[64 * 24], Jsh[64 * 24];
        for (int i = t; i < 64 * 19; i += 256)
            js[i] = (v0 * 19 + i < Vn * 19) ? jreg[v0 * 19 + i] : 0.f;
        for (int i = t; i < 64 * 24; i += 256) {
            wsh[i] = (v0 * 24 + i < Vn * 24) ? wts[v0 * 24 + i] : 0.f;
            Jsh[i] = (v0 * 24 + i < Vn * 24) ? Jreg[v0 * 24 + i] : 0.f;
        }
        __syncthreads();
        for (int s = t; s < 4096; s += 256) { // 512 cols x 8 v-groups
            int col = s >> 3, vg = s & 7;
            int kb = (v0 >> 5) + (vg >> 2);
            bf16x8 o;
            #pragma unroll
            for (int j = 0; j < 8; ++j) {
                int vl = vg * 8 + j;
                float val = 0.f;
                if (col < 456)      val = js[vl * 19 + col / 24] * wsh[vl * 24 + col % 24];
                else if (col < 480) val = Jsh[vl * 24 + (col - 456)];
                o[j] = (short)f2bf(val);
            }
            *(bf16x8*)(Bf + ((size_t)(col >> 4) * NKB + kb) * 512
                          + (size_t)((col & 15) + (vg & 3) * 16) * 8) = o;
        }
        return;
    }
    // ---- part C: zero Jacc (792 floats) + barrier state
    for (int i = t; i < 792; i += 256) Jacc[i] = 0.f;
    if (t == 0) bar[0] = 0u;
}

// ---------- K1: c-split 32x64 register-fragment MFMA, KSEG=12, depth-3 ----------
__device__ __forceinline__ void k1_load(bf16x8 (&a)[2], bf16x8 (&b)[4],
    const unsigned short* __restrict__ ap, const unsigned short* __restrict__ bp, int i)
{
    a[0] = *(const bf16x8*)(ap + (size_t)(0 * NKB + i) * 512);
    a[1] = *(const bf16x8*)(ap + (size_t)(1 * NKB + i) * 512);
    b[0] = *(const bf16x8*)(bp + (size_t)(0 * NKB + i) * 512);
    b[1] = *(const bf16x8*)(bp + (size_t)(1 * NKB + i) * 512);
    b[2] = *(const bf16x8*)(bp + (size_t)(2 * NKB + i) * 512);
    b[3] = *(const bf16x8*)(bp + (size_t)(3 * NKB + i) * 512);
}

__global__ __launch_bounds__(64) void k1_mfma(
    const unsigned short* __restrict__ Af, const unsigned short* __restrict__ Bf,
    float* __restrict__ P, float* __restrict__ Jacc)
{
    int l = threadIdx.x;
    int wid = blockIdx.x;                 // 2016 = KSEG * 3c * 7mt * 8nt
    int kseg = wid / 168; int r = wid % 168;
    int c = r / 56; r %= 56;
    int mt = r >> 3, nt = r & 7;
    int kb0 = kseg * KCH;

    const unsigned short* ap = Af + ((size_t)(c * NMG + mt * 2) * NKB + kb0) * 512 + l * 8;
    const unsigned short* bp = Bf + ((size_t)(nt * 4) * NKB + kb0) * 512 + l * 8;

    floatx4 acc[2][4];
    #pragma unroll
    for (int mi = 0; mi < 2; ++mi)
        #pragma unroll
        for (int ni = 0; ni < 4; ++ni) acc[mi][ni] = floatx4{0.f, 0.f, 0.f, 0.f};

    bf16x8 a[3][2], b[3][4];
    k1_load(a[0], b[0], ap, bp, 0);
    k1_load(a[1], b[1], ap, bp, 1);
    #pragma unroll
    for (int i = 0; i < KCH; ++i) {
        if (i + 2 < KCH) k1_load(a[(i + 2) % 3], b[(i + 2) % 3], ap, bp, i + 2);
        bf16x8 (&ac)[2] = a[i % 3];
        bf16x8 (&bc)[4] = b[i % 3];
        #pragma unroll
        for (int mi = 0; mi < 2; ++mi)
            #pragma unroll
            for (int ni = 0; ni < 4; ++ni)
                acc[mi][ni] = __builtin_amdgcn_mfma_f32_16x16x32_bf16(ac[mi], bc[ni], acc[mi][ni], 0, 0, 0);
    }
    // epilogue: C/D col=l&15 (B col), row=(l>>4)*4+reg (q) -> float4 stores
    float* Ps = P + (size_t)kseg * WR * QT;
    int lr = l & 15, rq = (l >> 4) * 4;
    #pragma unroll
    for (int mi = 0; mi < 2; ++mi)
        #pragma unroll
        for (int ni = 0; ni < 4; ++ni) {
            int col = nt * 64 + ni * 16 + lr;
            if (col < NCOL) {
                int q0 = mt * 32 + mi * 16 + rq;
                *(floatx4*)(Ps + (size_t)(col * 3 + c) * QT + q0) = acc[mi][ni];
            }
        }
    // J contribution: cols 456..479, q in 1..11 -> Jacc[((col-456)*3+c)*11 + q-1]
    if (mt == 0 && nt == 7 && rq < 12) {
        #pragma unroll
        for (int ni = 0; ni < 2; ++ni) {
            int col = 448 + ni * 16 + lr;
            if (col >= 456 && col < 480) {
                #pragma unroll
                for (int rr = 0; rr < 4; ++rr) {
                    int q = rq + rr;
                    if (q >= 1 && q < 12)
                        atomicAdd(&Jacc[(size_t)((col - 456) * 3 + c) * 11 + (q - 1)],
                                  acc[0][ni][rr]);
                }
            }
        }
    }
}

// ---------- grid barrier: monotonic counter, agent scope (256 resident blocks) ----------
__device__ __forceinline__ void gbar(unsigned* bar, unsigned target) {
    __syncthreads();
    if (threadIdx.x == 0) {
        __hip_atomic_fetch_add(&bar[0], 1u, __ATOMIC_ACQ_REL, __HIP_MEMORY_SCOPE_AGENT);
        while (__hip_atomic_load(&bar[0], __ATOMIC_ACQUIRE, __HIP_MEMORY_SCOPE_AGENT) < target)
            __builtin_amdgcn_s_sleep(2);
    }
    __syncthreads();
}

// ---------- TAIL: phase1 (reduce P + per-batch prep) -> phase2 (k3) -> phase3 (k4) ----------
// 256 blocks x 256 threads; low register pressure in every phase.
__global__ __launch_bounds__(256) void tail_mega(
    const float* __restrict__ P, const float* __restrict__ Jacc,
    const float* __restrict__ beta, const float* __restrict__ theta,
    unsigned short* __restrict__ Wb3, float* __restrict__ w1g,
    unsigned short* __restrict__ xbf, float* __restrict__ RAg, float* __restrict__ tAg,
    float* __restrict__ Mg, const float* __restrict__ trans, float* __restrict__ out,
    unsigned* __restrict__ bar)
{
    __shared__ __align__(16) float smem[7080];   // 28.3 KB, reused per phase
    int t = threadIdx.x;

    // ---------------- phase 1a: reduce P -> Wb3 + w1g (flat threads) ----------------
    {
        int g = blockIdx.x * 256 + t;
        if (g < WR * 28) {
            int colc = g / 28, q0 = (g % 28) * 8;
            float v[8] = {0, 0, 0, 0, 0, 0, 0, 0};
            #pragma unroll
            for (int s = 0; s < KSEG; ++s) {
                const float4* p = (const float4*)(P + ((size_t)s * WR + colc) * QT + q0);
                float4 x0 = p[0], x1 = p[1];
                v[0] += x0.x; v[1] += x0.y; v[2] += x0.z; v[3] += x0.w;
                v[4] += x1.x; v[5] += x1.y; v[6] += x1.z; v[7] += x1.w;
            }
            if (colc < 1408) {
                bf16x8 o;
                #pragma unroll
                for (int j = 0; j < 8; ++j)
                    o[j] = (short)((colc < MC) ? f2bf(v[j]) : 0);
                *(bf16x8*)(Wb3 + ((size_t)(colc >> 4) * 7 + (q0 >> 5)) * 512
                               + (size_t)((colc & 15) + ((q0 >> 3) & 3) * 16) * 8) = o;
            }
            if (q0 == 0 && colc % 3 == 0 && colc < MC) w1g[colc / 3] = v[0];
        }
    }
    // ---------------- phase 1b: per-batch prep, one wave per b (4 b's/block) ----------------
    {
        int widx = t >> 6, l = t & 63;
        int b = blockIdx.x * 4 + widx;           // 0..1023
        float* Rs   = smem + widx * 640;         // 216
        float* Jl   = Rs + 216;                  // 72
        float* resR = Jl + 72;                   // 216
        float* rest = resR + 216;                // 72
        float* bet  = rest + 72;                 // 10

        if (l < 10) bet[l] = beta[b * 10 + l];
        if (l < 24) {
            float t0 = theta[b * 72 + l * 3 + 0];
            float t1 = theta[b * 72 + l * 3 + 1];
            float t2 = theta[b * 72 + l * 3 + 2];
            float e0 = t0 + 1e-8f, e1 = t1 + 1e-8f, e2 = t2 + 1e-8f;
            float angle = sqrtf(e0 * e0 + e1 * e1 + e2 * e2);
            float half = 0.5f * angle;
            float sh = sinf(half), ch = cosf(half);
            float s = sh / angle;
            float qx = t0 * s, qy = t1 * s, qz = t2 * s;
            float qn = sqrtf(ch * ch + qx * qx + qy * qy + qz * qz);
            float w = ch / qn, x = qx / qn, y = qy / qn, z = qz / qn;
            Rs[l * 9 + 0] = 1.f - 2.f * (y * y + z * z);
            Rs[l * 9 + 1] = 2.f * (x * y - w * z);
            Rs[l * 9 + 2] = 2.f * (x * z + w * y);
            Rs[l * 9 + 3] = 2.f * (x * y + w * z);
            Rs[l * 9 + 4] = 1.f - 2.f * (x * x + z * z);
            Rs[l * 9 + 5] = 2.f * (y * z - w * x);
            Rs[l * 9 + 6] = 2.f * (x * z - w * y);
            Rs[l * 9 + 7] = 2.f * (y * z + w * x);
            Rs[l * 9 + 8] = 1.f - 2.f * (x * x + y * y);
        }
        __syncthreads();
        for (int idx = l; idx < 72; idx += 64) {
            const float* basep = Jacc + (size_t)idx * 11;
            float acc = basep[0];
            #pragma unroll
            for (int n = 0; n < 10; ++n) acc += bet[n] * basep[1 + n];
            Jl[idx] = acc;
        }
        for (int q = l; q < QT; q += 64) {
            float xv = 0.f;
            if (q == 1) xv = 1.f;
            else if (q >= 2 && q < 12) xv = bet[q - 2];
            else if (q >= 12 && q < 219) {
                int p = q - 12;
                int jj = 1 + p / 9, e = p % 9;
                float rr = Rs[jj * 9 + e];
                if (e == 0 || e == 4 || e == 8) rr -= 1.f;
                xv = rr;
            }
            xbf[((size_t)(b >> 4) * 7 + (q >> 5)) * 512
                + (size_t)((b & 15) + ((q >> 3) & 3) * 16) * 8 + (q & 7)] = f2bf(xv);
        }
        __syncthreads();
        if (l == 0) {
            const int par[24] = {-1,0,0,0,1,2,3,4,5,6,7,8,9,9,9,12,13,14,16,17,18,19,20,21};
            #pragma unroll
            for (int rr = 0; rr < 3; ++rr) {
                resR[rr * 3 + 0] =  Rs[rr * 3 + 0];
                resR[rr * 3 + 1] = -Rs[rr * 3 + 1];
                resR[rr * 3 + 2] = -Rs[rr * 3 + 2];
                rest[rr] = Jl[rr];
            }
            for (int i = 1; i < 24; ++i) {
                int p = par[i];
                float t0 = Jl[i * 3 + 0] - Jl[p * 3 + 0];
                float t1 = Jl[i * 3 + 1] - Jl[p * 3 + 1];
                float t2 = Jl[i * 3 + 2] - Jl[p * 3 + 2];
                #pragma unroll
                for (int rr = 0; rr < 3; ++rr) {
                    float a0 = resR[p * 9 + rr * 3 + 0], a1 = resR[p * 9 + rr * 3 + 1], a2 = resR[p * 9 + rr * 3 + 2];
                    resR[i * 9 + rr * 3 + 0] = a0 * Rs[i * 9 + 0] + a1 * Rs[i * 9 + 3] + a2 * Rs[i * 9 + 6];
                    resR[i * 9 + rr * 3 + 1] = a0 * Rs[i * 9 + 1] + a1 * Rs[i * 9 + 4] + a2 * Rs[i * 9 + 7];
                    resR[i * 9 + rr * 3 + 2] = a0 * Rs[i * 9 + 2] + a1 * Rs[i * 9 + 5] + a2 * Rs[i * 9 + 8];
                    rest[i * 3 + rr] = a0 * t0 + a1 * t1 + a2 * t2 + rest[p * 3 + rr];
                }
            }
        }
        __syncthreads();
        for (int idx = l; idx < 216; idx += 64)
            RAg[(size_t)b * 216 + idx] = resR[idx];
        if (l < 72) {
            int j = l / 3, c = l % 3;
            tAg[(size_t)b * 72 + l] = rest[j * 3 + c]
                - (resR[j * 9 + c * 3 + 0] * Jl[j * 3 + 0] + resR[j * 9 + c * 3 + 1] * Jl[j * 3 + 1]
                 + resR[j * 9 + c * 3 + 2] * Jl[j * 3 + 2]);
        }
    }
    gbar(bar, 256);

    // ---------------- phase 2: k3 (704 waves over 176 blocks' worth) ----------------
    {
        int wt = blockIdx.x * 4 + (t >> 6);
        if (wt < 704) {
            int blk = wt >> 2, w = wt & 3, l = t & 63;
            int wm = w & 1, wn = w >> 1;
            int ct = blk % 22, bt = blk / 22;
            int mg0 = ct * 4 + wm * 2;
            int bg0 = bt * 8 + wn * 4;
            const unsigned short* ap = Wb3 + (size_t)mg0 * 7 * 512 + l * 8;
            const unsigned short* bp = xbf + (size_t)bg0 * 7 * 512 + l * 8;

            floatx4 acc[2][4];
            #pragma unroll
            for (int mi = 0; mi < 2; ++mi)
                #pragma unroll
                for (int ni = 0; ni < 4; ++ni) acc[mi][ni] = floatx4{0.f, 0.f, 0.f, 0.f};

            #pragma unroll
            for (int kk = 0; kk < 7; ++kk) {
                bf16x8 a0 = *(const bf16x8*)(ap + (size_t)(0 * 7 + kk) * 512);
                bf16x8 a1 = *(const bf16x8*)(ap + (size_t)(1 * 7 + kk) * 512);
                bf16x8 b0 = *(const bf16x8*)(bp + (size_t)(0 * 7 + kk) * 512);
                bf16x8 b1 = *(const bf16x8*)(bp + (size_t)(1 * 7 + kk) * 512);
                bf16x8 b2 = *(const bf16x8*)(bp + (size_t)(2 * 7 + kk) * 512);
                bf16x8 b3 = *(const bf16x8*)(bp + (size_t)(3 * 7 + kk) * 512);
                acc[0][0] = __builtin_amdgcn_mfma_f32_16x16x32_bf16(a0, b0, acc[0][0], 0, 0, 0);
                acc[0][1] = __builtin_amdgcn_mfma_f32_16x16x32_bf16(a0, b1, acc[0][1], 0, 0, 0);
                acc[0][2] = __builtin_amdgcn_mfma_f32_16x16x32_bf16(a0, b2, acc[0][2], 0, 0, 0);
                acc[0][3] = __builtin_amdgcn_mfma_f32_16x16x32_bf16(a0, b3, acc[0][3], 0, 0, 0);
                acc[1][0] = __builtin_amdgcn_mfma_f32_16x16x32_bf16(a1, b0, acc[1][0], 0, 0, 0);
                acc[1][1] = __builtin_amdgcn_mfma_f32_16x16x32_bf16(a1, b1, acc[1][1], 0, 0, 0);
                acc[1][2] = __builtin_amdgcn_mfma_f32_16x16x32_bf16(a1, b2, acc[1][2], 0, 0, 0);
                acc[1][3] = __builtin_amdgcn_mfma_f32_16x16x32_bf16(a1, b3, acc[1][3], 0, 0, 0);
            }
            int lr = l & 15, rq = (l >> 4) * 4;
            #pragma unroll
            for (int mi = 0; mi < 2; ++mi)
                #pragma unroll
                for (int ni = 0; ni < 4; ++ni) {
                    int b  = bt * 128 + wn * 64 + ni * 16 + lr;
                    int cc = (mg0 + mi) * 16 + rq;
                    if (cc < MC)
                        *(floatx4*)(Mg + (size_t)b * MC + cc) = acc[mi][ni];
                }
        }
    }
    gbar(bar, 512);

    // ---------------- phase 3: k4 combine (all 256 blocks, 4 b's each) ----------------
    {
        float* w1s = smem;            // 456
        float* Ms  = smem + 456;      // 4*MC = 5472
        float* RAs = smem + 5928;     // 864
        float* tAs = smem + 6792;     // 288
        int b0 = blockIdx.x * 4;
        for (int i = t; i < 456; i += 256) w1s[i] = w1g[i];
        for (int i = t; i < 4 * MC; i += 256) Ms[i] = Mg[(size_t)b0 * MC + i];
        for (int i = t; i < 4 * 216; i += 256) RAs[i] = RAg[(size_t)b0 * 216 + i];
        for (int i = t; i < 4 * 72; i += 256) tAs[i] = tAg[(size_t)b0 * 72 + i];
        __syncthreads();
        if (t < 228) {
            int lb = t / 57, kc = t % 57;
            int k = kc / 3, c = kc % 3;
            int b = b0 + lb;
            float acc = trans[b * 3 + c];
            const float* Mrow = Ms + lb * MC;
            const float* RAr  = RAs + lb * 216;
            const float* tAr  = tAs + lb * 72;
            #pragma unroll
            for (int j = 0; j < 24; ++j) {
                int kj = k * 24 + j;
                float m0 = Mrow[kj * 3 + 0], m1 = Mrow[kj * 3 + 1], m2 = Mrow[kj * 3 + 2];
                acc += RAr[j * 9 + c * 3 + 0] * m0
                     + RAr[j * 9 + c * 3 + 1] * m1
                     + RAr[j * 9 + c * 3 + 2] * m2
                     + tAr[j * 3 + c] * w1s[kj];
            }
            out[b * 57 + kc] = acc;
        }
    }
}

extern "C" void kernel_launch(void* const* d_in, const int* in_sizes, int n_in,
                              void* d_out, int out_size, void* d_ws, size_t ws_size,
                              hipStream_t stream)
{
    const float* beta  = (const float*)d_in[0];
    const float* theta = (const float*)d_in[1];
    const float* trans = (const float*)d_in[2];
    const float* vt    = (const float*)d_in[3];
    const float* sdirs = (const float*)d_in[4];
    const float* Jreg  = (const float*)d_in[5];
    const float* pdirs = (const float*)d_in[6];
    const float* jreg  = (const float*)d_in[7];
    const float* wts   = (const float*)d_in[8];
    float* out = (float*)d_out;
    int B = in_sizes[0] / 10;   // 1024

    // workspace layout (~45 MB), all 16B-aligned
    unsigned short* Af  = (unsigned short*)d_ws;                 // 42*216*512
    unsigned short* Bf  = Af + (size_t)42 * NKB * 512;           // 32*216*512
    unsigned short* Wb3 = Bf + (size_t)32 * NKB * 512;           // 88*7*512
    unsigned short* xbf = Wb3 + (size_t)88 * 7 * 512;            // 64*7*512
    float* P    = (float*)(xbf + (size_t)64 * 7 * 512);          // KSEG*WR*QT
    float* Jacc = P + (size_t)KSEG * WR * QT;                    // 792
    float* w1g  = Jacc + 792;                                    // 456
    float* RAg  = w1g + 456;                                     // B*216
    float* tAg  = RAg + (size_t)B * 216;                         // B*72
    float* Mg   = tAg + (size_t)B * 72;                          // B*MC
    unsigned* bar = (unsigned*)(Mg + (size_t)B * MC);            // 1

    k0_build<<<dim3(756 + 108 + 1), 256, 0, stream>>>(
        vt, sdirs, pdirs, Jreg, jreg, wts, Af, Bf, Jacc, bar);
    k1_mfma<<<dim3(168 * KSEG), 64, 0, stream>>>(Af, Bf, P, Jacc);
    tail_mega<<<dim3(256), 256, 0, stream>>>(
        P, Jacc, beta, theta, Wb3, w1g, xbf, RAg, tAg, Mg, trans, out, bar);
}

// Round 10
// 147.092 us; speedup vs baseline: 1.8036x; 1.3189x over previous
//
#include <hip/hip_runtime.h>
#include <hip/hip_bf16.h>

// SMPL collapsed-form. R10: R6 dispatch structure (5 kernels, no grid barriers)
// + R9's k1 (KSEG=12, depth-3 prefetch, 2016 single-wave blocks).
// B=1024, V=6890, NB=10, NJ=24, NP=207, NK=19.
constexpr int Vn   = 6890;
constexpr int VC3  = 20670;   // V*3
constexpr int NKB  = 216;     // K blocks of 32 (K padded to 6912)
constexpr int QT   = 224;     // q rows: [ones, v_template, 10 shapedirs, 207 posedirs]
constexpr int NMG  = 14;      // QT/16 m-frag groups per c-plane
constexpr int NCOL = 480;     // 456 (k,j) cols + 24 Jreg cols
constexpr int WR   = 1440;    // W rows transposed = 480*3
constexpr int MC   = 1368;    // 456*3
constexpr int KSEG = 12;      // K split for k1 (216/12 = 18 kb per wave)
constexpr int KCH  = 18;      // k-blocks per wave
constexpr int RB   = 158;     // reduce blocks in k12 (1440*28/256 rounded up)

using bf16x8  = __attribute__((ext_vector_type(8))) short;
using floatx4 = __attribute__((ext_vector_type(4))) float;

__device__ __forceinline__ unsigned short f2bf(float f) {
    unsigned int u = __float_as_uint(f);
    unsigned int r = (u + 0x7FFFu + ((u >> 16) & 1u)) >> 16;
    return (unsigned short)r;
}

// ---------- K0: build Af [42][216] frags, Bf [32][216] frags, zero Jacc ----------
// frag element (lane l, j): row = base + (l&15), k = kb*32 + (l>>4)*8 + j
__global__ __launch_bounds__(256) void k0_build(
    const float* __restrict__ vt, const float* __restrict__ sdirs,
    const float* __restrict__ pdirs, const float* __restrict__ Jreg,
    const float* __restrict__ jreg, const float* __restrict__ wts,
    unsigned short* __restrict__ Af, unsigned short* __restrict__ Bf,
    float* __restrict__ Jacc)
{
    int bx = blockIdx.x, t = threadIdx.x;
    if (bx < 756) {                           // ---- part A: 224 q x 864 chunks of 8 v
        int g = bx * 256 + t;                 // < 193536 = 224*864
        int q = g / 864, u = g % 864;
        int v0 = u * 8, base = 3 * v0;
        float buf[24];
        if (q == 0) {
            #pragma unroll
            for (int i = 0; i < 24; ++i) buf[i] = (v0 + i / 3 < Vn) ? 1.f : 0.f;
        } else {
            const float* src = nullptr;
            if (q == 1) src = vt;
            else if (q >= 2 && q < 12)   src = sdirs + (size_t)(q - 2) * VC3;
            else if (q >= 12 && q < 219) src = pdirs + (size_t)(q - 12) * VC3;
            if (src && base + 23 < VC3) {
                #pragma unroll
                for (int i = 0; i < 12; ++i) {     // rows only 8B-aligned -> float2
                    float2 f = *(const float2*)(src + base + 2 * i);
                    buf[2 * i] = f.x; buf[2 * i + 1] = f.y;
                }
            } else {
                #pragma unroll
                for (int i = 0; i < 24; ++i)
                    buf[i] = (src && base + i < VC3) ? src[base + i] : 0.f;
            }
        }
        int kb = u >> 2, quad = u & 3, mg = q >> 4;
        size_t foff = (size_t)((q & 15) + quad * 16) * 8;
        #pragma unroll
        for (int c = 0; c < 3; ++c) {
            bf16x8 o;
            #pragma unroll
            for (int j = 0; j < 8; ++j) o[j] = (short)f2bf(buf[3 * j + c]);
            *(bf16x8*)(Af + ((size_t)(c * NMG + mg) * NKB + kb) * 512 + foff) = o;
        }
        return;
    }
    bx -= 756;
    if (bx < 108) {                           // ---- part B (108 blocks, 64 v each)
        int v0 = bx * 64;
        __shared__ float js[64 * 19], wsh[64 * 24], Jsh[64 * 24];
        for (int i = t; i < 64 * 19; i += 256)
            js[i] = (v0 * 19 + i < Vn * 19) ? jreg[v0 * 19 + i] : 0.f;
        for (int i = t; i < 64 * 24; i += 256) {
            wsh[i] = (v0 * 24 + i < Vn * 24) ? wts[v0 * 24 + i] : 0.f;
            Jsh[i] = (v0 * 24 + i < Vn * 24) ? Jreg[v0 * 24 + i] : 0.f;
        }
        __syncthreads();
        for (int s = t; s < 4096; s += 256) { // 512 cols x 8 v-groups
            int col = s >> 3, vg = s & 7;
            int kb = (v0 >> 5) + (vg >> 2);
            bf16x8 o;
            #pragma unroll
            for (int j = 0; j < 8; ++j) {
                int vl = vg * 8 + j;
                float val = 0.f;
                if (col < 456)      val = js[vl * 19 + col / 24] * wsh[vl * 24 + col % 24];
                else if (col < 480) val = Jsh[vl * 24 + (col - 456)];
                o[j] = (short)f2bf(val);
            }
            *(bf16x8*)(Bf + ((size_t)(col >> 4) * NKB + kb) * 512
                          + (size_t)((col & 15) + (vg & 3) * 16) * 8) = o;
        }
        return;
    }
    // ---- part C: zero Jacc (792 floats)
    for (int i = t; i < 792; i += 256) Jacc[i] = 0.f;
}

// ---------- K1: c-split 32x64 register-fragment MFMA, KSEG=12, depth-3 (R9) ----------
__device__ __forceinline__ void k1_load(bf16x8 (&a)[2], bf16x8 (&b)[4],
    const unsigned short* __restrict__ ap, const unsigned short* __restrict__ bp, int i)
{
    a[0] = *(const bf16x8*)(ap + (size_t)(0 * NKB + i) * 512);
    a[1] = *(const bf16x8*)(ap + (size_t)(1 * NKB + i) * 512);
    b[0] = *(const bf16x8*)(bp + (size_t)(0 * NKB + i) * 512);
    b[1] = *(const bf16x8*)(bp + (size_t)(1 * NKB + i) * 512);
    b[2] = *(const bf16x8*)(bp + (size_t)(2 * NKB + i) * 512);
    b[3] = *(const bf16x8*)(bp + (size_t)(3 * NKB + i) * 512);
}

__global__ __launch_bounds__(64) void k1_mfma(
    const unsigned short* __restrict__ Af, const unsigned short* __restrict__ Bf,
    float* __restrict__ P, float* __restrict__ Jacc)
{
    int l = threadIdx.x;
    int wid = blockIdx.x;                 // 2016 = KSEG * 3c * 7mt * 8nt
    int kseg = wid / 168; int r = wid % 168;
    int c = r / 56; r %= 56;
    int mt = r >> 3, nt = r & 7;
    int kb0 = kseg * KCH;

    const unsigned short* ap = Af + ((size_t)(c * NMG + mt * 2) * NKB + kb0) * 512 + l * 8;
    const unsigned short* bp = Bf + ((size_t)(nt * 4) * NKB + kb0) * 512 + l * 8;

    floatx4 acc[2][4];
    #pragma unroll
    for (int mi = 0; mi < 2; ++mi)
        #pragma unroll
        for (int ni = 0; ni < 4; ++ni) acc[mi][ni] = floatx4{0.f, 0.f, 0.f, 0.f};

    bf16x8 a[3][2], b[3][4];
    k1_load(a[0], b[0], ap, bp, 0);
    k1_load(a[1], b[1], ap, bp, 1);
    #pragma unroll
    for (int i = 0; i < KCH; ++i) {
        if (i + 2 < KCH) k1_load(a[(i + 2) % 3], b[(i + 2) % 3], ap, bp, i + 2);
        bf16x8 (&ac)[2] = a[i % 3];
        bf16x8 (&bc)[4] = b[i % 3];
        #pragma unroll
        for (int mi = 0; mi < 2; ++mi)
            #pragma unroll
            for (int ni = 0; ni < 4; ++ni)
                acc[mi][ni] = __builtin_amdgcn_mfma_f32_16x16x32_bf16(ac[mi], bc[ni], acc[mi][ni], 0, 0, 0);
    }
    // epilogue: C/D col=l&15 (B col), row=(l>>4)*4+reg (q) -> float4 stores
    float* Ps = P + (size_t)kseg * WR * QT;
    int lr = l & 15, rq = (l >> 4) * 4;
    #pragma unroll
    for (int mi = 0; mi < 2; ++mi)
        #pragma unroll
        for (int ni = 0; ni < 4; ++ni) {
            int col = nt * 64 + ni * 16 + lr;
            if (col < NCOL) {
                int q0 = mt * 32 + mi * 16 + rq;
                *(floatx4*)(Ps + (size_t)(col * 3 + c) * QT + q0) = acc[mi][ni];
            }
        }
    // J contribution: cols 456..479, q in 1..11 -> Jacc[((col-456)*3+c)*11 + q-1]
    if (mt == 0 && nt == 7 && rq < 12) {
        #pragma unroll
        for (int ni = 0; ni < 2; ++ni) {
            int col = 448 + ni * 16 + lr;
            if (col >= 456 && col < 480) {
                #pragma unroll
                for (int rr = 0; rr < 4; ++rr) {
                    int q = rq + rr;
                    if (q >= 1 && q < 12)
                        atomicAdd(&Jacc[(size_t)((col - 456) * 3 + c) * 11 + (q - 1)],
                                  acc[0][ni][rr]);
                }
            }
        }
    }
}

// ---------- K12: blocks < RB reduce P -> Wb3 + w1g; blocks >= RB per-batch prep ----------
__global__ __launch_bounds__(256) void k12_reduce_prep(
    const float* __restrict__ P, const float* __restrict__ Jacc,
    const float* __restrict__ beta, const float* __restrict__ theta,
    unsigned short* __restrict__ Wb3, float* __restrict__ w1g,
    unsigned short* __restrict__ xbf, float* __restrict__ RAg, float* __restrict__ tAg)
{
    int t = threadIdx.x;
    if (blockIdx.x < RB) {                    // ---------- reduce path
        int g = blockIdx.x * 256 + t;
        if (g >= WR * 28) return;
        int colc = g / 28, q0 = (g % 28) * 8;
        float v[8] = {0, 0, 0, 0, 0, 0, 0, 0};
        #pragma unroll
        for (int s = 0; s < KSEG; ++s) {
            const float4* p = (const float4*)(P + ((size_t)s * WR + colc) * QT + q0);
            float4 x0 = p[0], x1 = p[1];
            v[0] += x0.x; v[1] += x0.y; v[2] += x0.z; v[3] += x0.w;
            v[4] += x1.x; v[5] += x1.y; v[6] += x1.z; v[7] += x1.w;
        }
        if (colc < 1408) {                    // Wb3 A-frag (zeros for cc in [MC,1408))
            bf16x8 o;
            #pragma unroll
            for (int j = 0; j < 8; ++j)
                o[j] = (short)((colc < MC) ? f2bf(v[j]) : 0);
            *(bf16x8*)(Wb3 + ((size_t)(colc >> 4) * 7 + (q0 >> 5)) * 512
                           + (size_t)((colc & 15) + ((q0 >> 3) & 3) * 16) * 8) = o;
        }
        if (q0 == 0 && colc % 3 == 0 && colc < MC) w1g[colc / 3] = v[0];
        return;
    }
    // ---------- prep path (one block per batch element)
    int b = blockIdx.x - RB;
    __shared__ float Rs[24][9];
    __shared__ float Jl[24][3];
    __shared__ float resR[24][9];
    __shared__ float rest[24][3];
    __shared__ float bet[10];

    if (t < 10) bet[t] = beta[b * 10 + t];
    if (t < 24) {
        float t0 = theta[b * 72 + t * 3 + 0];
        float t1 = theta[b * 72 + t * 3 + 1];
        float t2 = theta[b * 72 + t * 3 + 2];
        float e0 = t0 + 1e-8f, e1 = t1 + 1e-8f, e2 = t2 + 1e-8f;
        float angle = sqrtf(e0 * e0 + e1 * e1 + e2 * e2);
        float half = 0.5f * angle;
        float sh = sinf(half), ch = cosf(half);
        float s = sh / angle;
        float qx = t0 * s, qy = t1 * s, qz = t2 * s;
        float qn = sqrtf(ch * ch + qx * qx + qy * qy + qz * qz);
        float w = ch / qn, x = qx / qn, y = qy / qn, z = qz / qn;
        Rs[t][0] = 1.f - 2.f * (y * y + z * z);
        Rs[t][1] = 2.f * (x * y - w * z);
        Rs[t][2] = 2.f * (x * z + w * y);
        Rs[t][3] = 2.f * (x * y + w * z);
        Rs[t][4] = 1.f - 2.f * (x * x + z * z);
        Rs[t][5] = 2.f * (y * z - w * x);
        Rs[t][6] = 2.f * (x * z - w * y);
        Rs[t][7] = 2.f * (y * z + w * x);
        Rs[t][8] = 1.f - 2.f * (x * x + y * y);
    }
    __syncthreads();
    // J[j][c] from Jacc: base(q=1 row) + sum_n beta[n] * coef(q=2+n)
    if (t < 72) {
        const float* basep = Jacc + (size_t)t * 11;
        float acc = basep[0];
        #pragma unroll
        for (int n = 0; n < 10; ++n) acc += bet[n] * basep[1 + n];
        Jl[t / 3][t % 3] = acc;
    }
    // x vector in k3 B-fragment layout
    for (int q = t; q < QT; q += 256) {
        float xv = 0.f;
        if (q == 1) xv = 1.f;
        else if (q >= 2 && q < 12) xv = bet[q - 2];
        else if (q >= 12 && q < 219) {
            int p = q - 12;
            int jj = 1 + p / 9, e = p % 9;
            float rr = Rs[jj][e];
            if (e == 0 || e == 4 || e == 8) rr -= 1.f;
            xv = rr;
        }
        xbf[((size_t)(b >> 4) * 7 + (q >> 5)) * 512
            + (size_t)((b & 15) + ((q >> 3) & 3) * 16) * 8 + (q & 7)] = f2bf(xv);
    }
    __syncthreads();
    if (t == 0) {
        const int par[24] = {-1,0,0,0,1,2,3,4,5,6,7,8,9,9,9,12,13,14,16,17,18,19,20,21};
        #pragma unroll
        for (int rr = 0; rr < 3; ++rr) {
            resR[0][rr * 3 + 0] =  Rs[0][rr * 3 + 0];
            resR[0][rr * 3 + 1] = -Rs[0][rr * 3 + 1];
            resR[0][rr * 3 + 2] = -Rs[0][rr * 3 + 2];
            rest[0][rr] = Jl[0][rr];
        }
        for (int i = 1; i < 24; ++i) {
            int p = par[i];
            float t0 = Jl[i][0] - Jl[p][0];
            float t1 = Jl[i][1] - Jl[p][1];
            float t2 = Jl[i][2] - Jl[p][2];
            #pragma unroll
            for (int rr = 0; rr < 3; ++rr) {
                float a0 = resR[p][rr * 3 + 0], a1 = resR[p][rr * 3 + 1], a2 = resR[p][rr * 3 + 2];
                resR[i][rr * 3 + 0] = a0 * Rs[i][0] + a1 * Rs[i][3] + a2 * Rs[i][6];
                resR[i][rr * 3 + 1] = a0 * Rs[i][1] + a1 * Rs[i][4] + a2 * Rs[i][7];
                resR[i][rr * 3 + 2] = a0 * Rs[i][2] + a1 * Rs[i][5] + a2 * Rs[i][8];
                rest[i][rr] = a0 * t0 + a1 * t1 + a2 * t2 + rest[p][rr];
            }
        }
    }
    __syncthreads();
    if (t < 216) RAg[(size_t)b * 216 + t] = resR[t / 9][t % 9];
    if (t < 72) {
        int j = t / 3, c = t % 3;
        tAg[(size_t)b * 72 + t] = rest[j][c]
            - (resR[j][c * 3 + 0] * Jl[j][0] + resR[j][c * 3 + 1] * Jl[j][1]
             + resR[j][c * 3 + 2] * Jl[j][2]);
    }
}

// ---------- K3: Mg[b][cc] = sum_q W[cc][q]*x[b][q]; W as A-op -> float4 stores ----------
__global__ __launch_bounds__(256) void k3_mfma(
    const unsigned short* __restrict__ Wb3, const unsigned short* __restrict__ xbf,
    float* __restrict__ Mg)
{
    int w = threadIdx.x >> 6, l = threadIdx.x & 63;
    int wm = w & 1, wn = w >> 1;
    int ct = blockIdx.x % 22, bt = blockIdx.x / 22;
    int mg0 = ct * 4 + wm * 2;            // Wb3 groups (16 cc each)
    int bg0 = bt * 8 + wn * 4;            // xbf groups (16 b each)
    const unsigned short* ap = Wb3 + (size_t)mg0 * 7 * 512 + l * 8;
    const unsigned short* bp = xbf + (size_t)bg0 * 7 * 512 + l * 8;

    floatx4 acc[2][4];
    #pragma unroll
    for (int mi = 0; mi < 2; ++mi)
        #pragma unroll
        for (int ni = 0; ni < 4; ++ni) acc[mi][ni] = floatx4{0.f, 0.f, 0.f, 0.f};

    #pragma unroll
    for (int kk = 0; kk < 7; ++kk) {
        bf16x8 a0 = *(const bf16x8*)(ap + (size_t)(0 * 7 + kk) * 512);
        bf16x8 a1 = *(const bf16x8*)(ap + (size_t)(1 * 7 + kk) * 512);
        bf16x8 b0 = *(const bf16x8*)(bp + (size_t)(0 * 7 + kk) * 512);
        bf16x8 b1 = *(const bf16x8*)(bp + (size_t)(1 * 7 + kk) * 512);
        bf16x8 b2 = *(const bf16x8*)(bp + (size_t)(2 * 7 + kk) * 512);
        bf16x8 b3 = *(const bf16x8*)(bp + (size_t)(3 * 7 + kk) * 512);
        acc[0][0] = __builtin_amdgcn_mfma_f32_16x16x32_bf16(a0, b0, acc[0][0], 0, 0, 0);
        acc[0][1] = __builtin_amdgcn_mfma_f32_16x16x32_bf16(a0, b1, acc[0][1], 0, 0, 0);
        acc[0][2] = __builtin_amdgcn_mfma_f32_16x16x32_bf16(a0, b2, acc[0][2], 0, 0, 0);
        acc[0][3] = __builtin_amdgcn_mfma_f32_16x16x32_bf16(a0, b3, acc[0][3], 0, 0, 0);
        acc[1][0] = __builtin_amdgcn_mfma_f32_16x16x32_bf16(a1, b0, acc[1][0], 0, 0, 0);
        acc[1][1] = __builtin_amdgcn_mfma_f32_16x16x32_bf16(a1, b1, acc[1][1], 0, 0, 0);
        acc[1][2] = __builtin_amdgcn_mfma_f32_16x16x32_bf16(a1, b2, acc[1][2], 0, 0, 0);
        acc[1][3] = __builtin_amdgcn_mfma_f32_16x16x32_bf16(a1, b3, acc[1][3], 0, 0, 0);
    }
    int lr = l & 15, rq = (l >> 4) * 4;
    #pragma unroll
    for (int mi = 0; mi < 2; ++mi)
        #pragma unroll
        for (int ni = 0; ni < 4; ++ni) {
            int b  = bt * 128 + wn * 64 + ni * 16 + lr;
            int cc = (mg0 + mi) * 16 + rq;
            if (cc < MC)
                *(floatx4*)(Mg + (size_t)b * MC + cc) = acc[mi][ni];
        }
}

// ---------- K4: joints[b][k][c] = trans + sum_j RA[c,:].M + tA[c]*w1 ----------
__global__ __launch_bounds__(256) void k4_combine(
    const float* __restrict__ Mg, const float* __restrict__ RAg,
    const float* __restrict__ tAg, const float* __restrict__ w1g,
    const float* __restrict__ trans, float* __restrict__ out)
{
    __shared__ float w1s[456];
    __shared__ float Ms[4 * MC];
    __shared__ float RAs[4 * 216];
    __shared__ float tAs[4 * 72];
    int tid = threadIdx.x;
    int b0 = blockIdx.x * 4;
    for (int i = tid; i < 456; i += 256) w1s[i] = w1g[i];
    for (int i = tid; i < 4 * MC; i += 256) Ms[i] = Mg[(size_t)b0 * MC + i];
    for (int i = tid; i < 4 * 216; i += 256) RAs[i] = RAg[(size_t)b0 * 216 + i];
    for (int i = tid; i < 4 * 72; i += 256) tAs[i] = tAg[(size_t)b0 * 72 + i];
    __syncthreads();
    if (tid < 228) {
        int lb = tid / 57, kc = tid % 57;
        int k = kc / 3, c = kc % 3;
        int b = b0 + lb;
        float acc = trans[b * 3 + c];
        const float* Mrow = Ms + lb * MC;
        const float* RAr  = RAs + lb * 216;
        const float* tAr  = tAs + lb * 72;
        #pragma unroll
        for (int j = 0; j < 24; ++j) {
            int kj = k * 24 + j;
            float m0 = Mrow[kj * 3 + 0], m1 = Mrow[kj * 3 + 1], m2 = Mrow[kj * 3 + 2];
            acc += RAr[j * 9 + c * 3 + 0] * m0
                 + RAr[j * 9 + c * 3 + 1] * m1
                 + RAr[j * 9 + c * 3 + 2] * m2
                 + tAr[j * 3 + c] * w1s[kj];
        }
        out[b * 57 + kc] = acc;
    }
}

extern "C" void kernel_launch(void* const* d_in, const int* in_sizes, int n_in,
                              void* d_out, int out_size, void* d_ws, size_t ws_size,
                              hipStream_t stream)
{
    const float* beta  = (const float*)d_in[0];
    const float* theta = (const float*)d_in[1];
    const float* trans = (const float*)d_in[2];
    const float* vt    = (const float*)d_in[3];
    const float* sdirs = (const float*)d_in[4];
    const float* Jreg  = (const float*)d_in[5];
    const float* pdirs = (const float*)d_in[6];
    const float* jreg  = (const float*)d_in[7];
    const float* wts   = (const float*)d_in[8];
    float* out = (float*)d_out;
    int B = in_sizes[0] / 10;   // 1024

    // workspace layout (~45 MB), all 16B-aligned
    unsigned short* Af  = (unsigned short*)d_ws;                 // 42*216*512
    unsigned short* Bf  = Af + (size_t)42 * NKB * 512;           // 32*216*512
    unsigned short* Wb3 = Bf + (size_t)32 * NKB * 512;           // 88*7*512
    unsigned short* xbf = Wb3 + (size_t)88 * 7 * 512;            // 64*7*512
    float* P    = (float*)(xbf + (size_t)64 * 7 * 512);          // KSEG*WR*QT
    float* Jacc = P + (size_t)KSEG * WR * QT;                    // 792
    float* w1g  = Jacc + 792;                                    // 456
    float* RAg  = w1g + 456;                                     // B*216
    float* tAg  = RAg + (size_t)B * 216;                         // B*72
    float* Mg   = tAg + (size_t)B * 72;                          // B*MC

    k0_build<<<dim3(756 + 108 + 1), 256, 0, stream>>>(
        vt, sdirs, pdirs, Jreg, jreg, wts, Af, Bf, Jacc);
    k1_mfma<<<dim3(168 * KSEG), 64, 0, stream>>>(Af, Bf, P, Jacc);
    k12_reduce_prep<<<dim3(RB + B), 256, 0, stream>>>(
        P, Jacc, beta, theta, Wb3, w1g, xbf, RAg, tAg);
    k3_mfma<<<dim3((B / 128) * 22), 256, 0, stream>>>(Wb3, xbf, Mg);
    k4_combine<<<dim3(B / 4), 256, 0, stream>>>(Mg, RAg, tAg, w1g, trans, out);
}